// Round 8
// baseline (100.184 us; speedup 1.0000x reference)
//
#include <hip/hip_runtime.h>

// EWMA scan y_t = (1-a)*y_{t-1} + a*x_t, y_{-1} = first_offset.
// D-striped 3-phase chunked scan. Columns split into NS=2 stripes of 512 so
// that during each stripe's P1->P3 window the footprint (data_s 67MB + out_s
// 67MB + ws) fits the 256MB Infinity Cache => P3's data re-read is L3-served.
// Plain loads/stores (nt hints measured harmful: R4/R6). TCH=32 keeps 8
// waves/CU in streaming kernels; CCH=1024/stripe keeps phase2 ws cost low.

#define LT   32768
#define DC   1024
#define NS   2
#define SW   (DC / NS)        // 512 cols per stripe
#define SW4  (SW / 4)         // 128 float4 groups per stripe row
#define TCH  32               // timesteps per chunk
#define CCH  (LT / TCH)       // 1024 chunks
#define D4   (DC / 4)

typedef float nf4 __attribute__((ext_vector_type(4)));

__global__ void ewma_p1(const nf4* __restrict__ data4,
                        nf4* __restrict__ zend4,
                        const float* __restrict__ alpha_p, int s) {
    const float alpha = alpha_p[0];
    const float decay = 1.0f - alpha;
    const int g = threadIdx.x;      // float4 group within stripe (0..127)
    const int c = blockIdx.x;       // chunk index
    const nf4* p = data4 + (size_t)c * TCH * D4 + s * SW4 + g;
    float z0 = 0.f, z1 = 0.f, z2 = 0.f, z3 = 0.f;
#pragma unroll
    for (int i = 0; i < TCH; ++i) {
        nf4 x = p[(size_t)i * D4];
        z0 = fmaf(decay, z0, alpha * x.x);
        z1 = fmaf(decay, z1, alpha * x.y);
        z2 = fmaf(decay, z2, alpha * x.z);
        z3 = fmaf(decay, z3, alpha * x.w);
    }
    nf4 zv; zv.x = z0; zv.y = z1; zv.z = z2; zv.w = z3;
    zend4[(size_t)c * D4 + s * SW4 + g] = zv;
}

// One wave per column d. Lane l owns chunks [l*CPL, (l+1)*CPL).
// Inter-chunk recurrence: S_c = r * S_{c-1} + e_c, r = decay^TCH.
__global__ void ewma_p2(const float* __restrict__ zend,
                        const float* __restrict__ first,
                        float* __restrict__ carry,
                        const float* __restrict__ alpha_p, int s) {
    const float alpha = alpha_p[0];
    const float decay = 1.0f - alpha;
    float r = decay;                 // decay^TCH via 5 squarings (TCH=32)
    r *= r; r *= r; r *= r; r *= r; r *= r;

    const int lane = threadIdx.x & 63;
    const int d = s * SW + ((blockIdx.x * blockDim.x + threadIdx.x) >> 6);
    constexpr int CPL = CCH / 64;   // 16 chunks per lane

    float e[CPL];
#pragma unroll
    for (int j = 0; j < CPL; ++j)
        e[j] = zend[(size_t)(lane * CPL + j) * DC + d];

    // lane-local aggregate with ratio r, zero init
    float A = 0.f;
#pragma unroll
    for (int j = 0; j < CPL; ++j) A = fmaf(r, A, e[j]);

    // q = r^CPL, CPL=16
    float q = r;
    q *= q; q *= q; q *= q; q *= q;

    // Kogge-Stone inclusive scan across 64 lanes
    float y = A;
    float p = q;
#pragma unroll
    for (int o = 1; o < 64; o <<= 1) {
        float prev = __shfl_up(y, o, 64);
        if (lane >= o) y = fmaf(p, prev, y);
        p = p * p;
    }
    float excl = __shfl_up(y, 1, 64);
    if (lane == 0) excl = 0.f;

    // decayed first_offset contribution: q^lane
    float qpow = 1.f;
    {
        float base = q;
        int e2 = lane;
        while (e2) { if (e2 & 1) qpow *= base; base *= base; e2 >>= 1; }
    }
    float S = fmaf(qpow, first[d], excl);  // carry entering lane's first chunk

#pragma unroll
    for (int j = 0; j < CPL; ++j) {
        const int c = lane * CPL + j;
        carry[(size_t)c * DC + d] = S;     // carry-in for chunk c
        S = fmaf(r, S, e[j]);
    }
}

__global__ void ewma_p3(const nf4* __restrict__ data4,
                        const nf4* __restrict__ carry4,
                        nf4* __restrict__ out4,
                        nf4* __restrict__ out_last4,
                        const float* __restrict__ alpha_p, int s) {
    const float alpha = alpha_p[0];
    const float decay = 1.0f - alpha;
    const int g = threadIdx.x;
    const int c = blockIdx.x;
    const nf4 cin = carry4[(size_t)c * D4 + s * SW4 + g];
    const nf4* p = data4 + (size_t)c * TCH * D4 + s * SW4 + g;
    nf4* o = out4 + (size_t)c * TCH * D4 + s * SW4 + g;
    float z0 = 0.f, z1 = 0.f, z2 = 0.f, z3 = 0.f, pw = 1.f;
#pragma unroll
    for (int i = 0; i < TCH; ++i) {
        nf4 x = p[(size_t)i * D4];       // L3-resident: fetched by P1(s)
        z0 = fmaf(decay, z0, alpha * x.x);
        z1 = fmaf(decay, z1, alpha * x.y);
        z2 = fmaf(decay, z2, alpha * x.z);
        z3 = fmaf(decay, z3, alpha * x.w);
        pw *= decay;
        nf4 yv;
        yv.x = fmaf(pw, cin.x, z0);
        yv.y = fmaf(pw, cin.y, z1);
        yv.z = fmaf(pw, cin.z, z2);
        yv.w = fmaf(pw, cin.w, z3);
        o[(size_t)i * D4] = yv;
    }
    if (c == CCH - 1) {
        nf4 yl;
        yl.x = fmaf(pw, cin.x, z0);
        yl.y = fmaf(pw, cin.y, z1);
        yl.z = fmaf(pw, cin.z, z2);
        yl.w = fmaf(pw, cin.w, z3);
        out_last4[s * SW4 + g] = yl;
    }
}

extern "C" void kernel_launch(void* const* d_in, const int* in_sizes, int n_in,
                              void* d_out, int out_size, void* d_ws, size_t ws_size,
                              hipStream_t stream) {
    const float* data    = (const float*)d_in[0];
    const float* first   = (const float*)d_in[1];
    const float* alpha_p = (const float*)d_in[2];
    float* out = (float*)d_out;

    float* zend  = (float*)d_ws;              // CCH*DC floats = 4 MB
    float* carry = zend + (size_t)CCH * DC;   // CCH*DC floats = 4 MB

    for (int s = 0; s < NS; ++s) {
        ewma_p1<<<CCH, SW4, 0, stream>>>(
            (const nf4*)data, (nf4*)zend, alpha_p, s);

        ewma_p2<<<SW / 4, 256, 0, stream>>>(
            zend, first, carry, alpha_p, s);

        ewma_p3<<<CCH, SW4, 0, stream>>>(
            (const nf4*)data, (const nf4*)carry, (nf4*)out,
            (nf4*)(out + (size_t)LT * DC), alpha_p, s);
    }
}